// Round 1
// baseline (646.229 us; speedup 1.0000x reference)
//
#include <hip/hip_runtime.h>
#include <hip/hip_bf16.h>

#define NROWS 8192
#define INF_ 256
#define OUTF 128
#define NEG_SLOPE 0.2f
#define CUTOFF 46.0f     // drop exp(e-m) terms below e^-46 ~ 1e-20 (f32-negligible)
#define CAP 1024         // candidate list capacity; flushed every 1024-j chunk

// ---------------- Kernel 1: Z = X @ W  (8192x256 @ 256x128, f32) ----------------
__global__ __launch_bounds__(256) void zk(const float* __restrict__ X,
                                          const float* __restrict__ W,
                                          float* __restrict__ Z) {
  __shared__ float Xs[8 * INF_];
  const int t = threadIdx.x;
  const long i0 = (long)blockIdx.x * 8;
  for (int idx = t; idx < 8 * INF_; idx += 256)
    Xs[idx] = X[i0 * INF_ + idx];
  __syncthreads();
  const int o = t & 127;
  const int rg = t >> 7;  // 0/1 -> rows rg*4 .. rg*4+3
  float a0 = 0.f, a1 = 0.f, a2 = 0.f, a3 = 0.f;
  const float* Xb = &Xs[rg * 4 * INF_];
#pragma unroll 4
  for (int k = 0; k < INF_; ++k) {
    const float wv = W[k * OUTF + o];   // coalesced across o, L2-resident
    a0 = fmaf(Xb[k], wv, a0);
    a1 = fmaf(Xb[INF_ + k], wv, a1);
    a2 = fmaf(Xb[2 * INF_ + k], wv, a2);
    a3 = fmaf(Xb[3 * INF_ + k], wv, a3);
  }
  const long zb = (i0 + (long)rg * 4) * OUTF + o;
  Z[zb] = a0;
  Z[zb + OUTF] = a1;
  Z[zb + 2 * OUTF] = a2;
  Z[zb + 3 * OUTF] = a3;
}

// ---------------- Kernel 2: r = Z @ a_src, c = Z @ a_dst (per-row dots) ----------------
__global__ __launch_bounds__(256) void sk(const float* __restrict__ Z,
                                          const float* __restrict__ a,
                                          float* __restrict__ rvec,
                                          float* __restrict__ cvec) {
  const int t = threadIdx.x;
  const int lane = t & 63, wave = t >> 6;
  const long i = (long)blockIdx.x * 4 + wave;
  const float2 z  = *(const float2*)&Z[i * OUTF + 2 * lane];
  const float2 as = *(const float2*)&a[2 * lane];
  const float2 ad = *(const float2*)&a[OUTF + 2 * lane];
  float r = z.x * as.x + z.y * as.y;
  float c = z.x * ad.x + z.y * ad.y;
#pragma unroll
  for (int off = 32; off > 0; off >>= 1) {
    r += __shfl_down(r, off, 64);
    c += __shfl_down(c, off, 64);
  }
  if (lane == 0) { rvec[i] = r; cvec[i] = c; }
}

// ---------------- Kernel 3: fused masked-softmax attention, one block per row ----------------
__global__ __launch_bounds__(256) void attn(const int* __restrict__ A,
                                            const float* __restrict__ Z,
                                            const float* __restrict__ rv,
                                            const float* __restrict__ cv,
                                            float* __restrict__ out) {
  __shared__ unsigned char s_adj[NROWS];   // 8 KB: compressed A row
  __shared__ int   s_jl[CAP];              // 4 KB
  __shared__ float s_wl[CAP];              // 4 KB
  __shared__ float s_fin[2 * OUTF];        // 1 KB
  __shared__ float s_red[4];
  __shared__ int   s_redi[4];
  __shared__ float s_bf[2];                // m, w0
  __shared__ int   s_bi[2];                // count0, pushA0
  __shared__ int   s_cnt;

  const int t = threadIdx.x;
  const int lane = t & 63, wave = t >> 6;
  const long i = blockIdx.x;

  if (t == 0) s_cnt = 0;
  const float ri = rv[i];

  const int4*   A4 = (const int4*)(A + i * NROWS);
  const float4* c4 = (const float4*)cv;

  // ---- scan 1: cmax over A==1, count of zeros; byte-compress A row into LDS
  float cmax = -INFINITY;
  int cnt0 = 0;
#pragma unroll
  for (int it = 0; it < 8; ++it) {
    const int idx = it * 256 + t;          // quad index; covers j = 4*idx..4*idx+3
    const int4   av = A4[idx];             // coalesced 16B/lane from HBM
    const float4 cq = c4[idx];             // L2-resident
    uchar4 b;
    b.x = (unsigned char)(av.x > 0);
    b.y = (unsigned char)(av.y > 0);
    b.z = (unsigned char)(av.z > 0);
    b.w = (unsigned char)(av.w > 0);
    if (av.x > 0) cmax = fmaxf(cmax, cq.x); else ++cnt0;
    if (av.y > 0) cmax = fmaxf(cmax, cq.y); else ++cnt0;
    if (av.z > 0) cmax = fmaxf(cmax, cq.z); else ++cnt0;
    if (av.w > 0) cmax = fmaxf(cmax, cq.w); else ++cnt0;
    *(uchar4*)(s_adj + idx * 4) = b;
  }
#pragma unroll
  for (int off = 32; off > 0; off >>= 1) {
    cmax = fmaxf(cmax, __shfl_down(cmax, off, 64));
    cnt0 += __shfl_down(cnt0, off, 64);
  }
  if (lane == 0) { s_red[wave] = cmax; s_redi[wave] = cnt0; }
  __syncthreads();
  if (t == 0) {
    const float cm = fmaxf(fmaxf(s_red[0], s_red[1]), fmaxf(s_red[2], s_red[3]));
    const int   c0 = s_redi[0] + s_redi[1] + s_redi[2] + s_redi[3];
    const float raw = ri + cm;                              // cm=-inf -> -inf (no A=1)
    const float emax = (raw >= 0.f) ? raw : NEG_SLOPE * raw; // lrelu, monotone => exact row max
    const float m = (c0 > 0) ? fmaxf(emax, 0.f) : emax;      // zeros present => e contains 0
    s_bf[0] = m;
    s_bf[1] = __expf(-m);          // weight of each A==0 entry
    s_bi[0] = c0;
    s_bi[1] = (m < CUTOFF) ? 1 : 0;  // if set: A==0 entries are real candidates (rare dense rows)
  }
  __syncthreads();
  const float m      = s_bf[0];
  const float w0     = s_bf[1];
  const int   count0 = s_bi[0];
  const int   pushA0 = s_bi[1];

  // ---- scan 2: collect contributing j's, accumulate sparse alpha @ Z
  float accr = 0.f;                  // this thread's partial for dim d, half g
  const int g = t >> 7, d = t & 127;
  float lsum = 0.f;

  for (int it = 0; it < 8; ++it) {
    const int idx = it * 256 + t;
    const float4 cq = c4[idx];
    const uchar4 b = *(const uchar4*)(s_adj + idx * 4);

#define DOE(comp, bb, qq)                                              \
    {                                                                  \
      float w_;                                                        \
      if (bb) {                                                        \
        const float raw_ = ri + (comp);                                \
        const float e_ = (raw_ >= 0.f) ? raw_ : NEG_SLOPE * raw_;      \
        const float dg_ = e_ - m;                                      \
        w_ = (dg_ >= -CUTOFF) ? __expf(dg_) : 0.f;                     \
      } else {                                                         \
        w_ = pushA0 ? w0 : 0.f;                                        \
      }                                                                \
      lsum += w_;                                                      \
      if (w_ > 0.f) {                                                  \
        const int p_ = atomicAdd(&s_cnt, 1);                           \
        s_jl[p_] = idx * 4 + (qq);                                     \
        s_wl[p_] = w_;                                                 \
      }                                                                \
    }
    DOE(cq.x, b.x, 0)
    DOE(cq.y, b.y, 1)
    DOE(cq.z, b.z, 2)
    DOE(cq.w, b.w, 3)
#undef DOE

    __syncthreads();                 // B1: all pushes of this chunk visible
    const int cn = s_cnt;            // uniform (no writes until B3)
    for (int k = g; k < cn; k += 2)  // halves process alternating candidates
      accr = fmaf(s_wl[k], Z[(long)s_jl[k] * OUTF + d], accr);
    __syncthreads();                 // B2: list consumption done
    if (t == 0) s_cnt = 0;
    __syncthreads();                 // B3: reset visible
  }

  // ---- denominator and epilogue
#pragma unroll
  for (int off = 32; off > 0; off >>= 1) lsum += __shfl_down(lsum, off, 64);
  if (lane == 0) s_red[wave] = lsum;
  __syncthreads();
  float ltot = s_red[0] + s_red[1] + s_red[2] + s_red[3];
  if (!pushA0) ltot += (float)count0 * w0;   // tiny exact correction for skipped zeros

  s_fin[t] = accr;
  __syncthreads();
  if (t < OUTF)
    out[i * OUTF + t] = (s_fin[t] + s_fin[t + OUTF]) / ltot;
}

extern "C" void kernel_launch(void* const* d_in, const int* in_sizes, int n_in,
                              void* d_out, int out_size, void* d_ws, size_t ws_size,
                              hipStream_t stream) {
  const float* X = (const float*)d_in[0];
  const int*   A = (const int*)d_in[1];
  const float* W = (const float*)d_in[2];
  const float* a = (const float*)d_in[3];
  float* out = (float*)d_out;

  float* Z    = (float*)d_ws;                  // 8192*128 f32 = 4 MB
  float* rvec = Z + (long)NROWS * OUTF;        // 32 KB
  float* cvec = rvec + NROWS;                  // 32 KB

  zk<<<NROWS / 8, 256, 0, stream>>>(X, W, Z);
  sk<<<NROWS / 4, 256, 0, stream>>>(Z, a, rvec, cvec);
  attn<<<NROWS, 256, 0, stream>>>(A, Z, rvec, cvec, out);
}